// Round 2
// baseline (2015.388 us; speedup 1.0000x reference)
//
#include <hip/hip_runtime.h>
#include <hip/hip_bf16.h>

#define HID 96
#define INDIM 128
#define OUTDIM 64
#define THID (3*HID)   // 288
#define NT 4

__device__ __forceinline__ float ldmix(const void* p, long i, int mode) {
    return mode ? ((const float*)p)[i]
                : __bfloat162float(((const __hip_bfloat16*)p)[i]);
}

// ---------------- dtype sniffer: fp32 data has uniform-random low 16 bits ----------------
__global__ void sniff_kernel(const unsigned int* xw, int* mode) {
    if (threadIdx.x == 0 && blockIdx.x == 0) {
        int cnt = 0;
        for (int i = 0; i < 4096; i++) {
            unsigned int low = xw[i] & 0xFFFFu;
            unsigned int e = (low >> 7) & 0xFFu;
            if (e >= 0xC0u) cnt++;   // |value| >= 2^65 or NaN/Inf as bf16: never for real data
        }
        *mode = (cnt > 256) ? 1 : 0;  // 1 = fp32 inputs, 0 = bf16 inputs
    }
}

// ---------------- x -> fp32 ----------------
__global__ void xconv_kernel(const void* x, float* __restrict__ x_f, const int* mode, int total) {
    int m = *mode;
    int tid = blockIdx.x*blockDim.x + threadIdx.x;
    if (tid < total) x_f[tid] = ldmix(x, tid, m);
}

// ---------------- weight prep: -> fp32, transpose GRU weights ----------------
// smallf layout: [0..95] b_in, [96..383] bih, [384..671] bhh, [672..735] b_out,
//                [736..751] tau_w2, [752..767] tau_b1, [768] tau_b2
__global__ void prep_kernel(const void* w_in, const void* b_in, const void* tau_w1,
                            const void* tau_b1, const void* tau_w2, const void* tau_b2,
                            const void* wih, const void* whh, const void* bih, const void* bhh,
                            const void* w_out, const void* b_out,
                            float* wihT, float* whhT, float* w_in_f, float* w_out_f,
                            float* tau_w1_f, float* smallf, const int* mode) {
    int m = *mode;
    int tid = blockIdx.x*blockDim.x + threadIdx.x;
    if (tid < THID*HID) {           // 27648: transpose [288,96] -> [96,288]
        int j = tid / HID, k = tid % HID;
        wihT[k*THID + j] = ldmix(wih, tid, m);
        whhT[k*THID + j] = ldmix(whh, tid, m);
    }
    if (tid < INDIM*HID)  w_in_f[tid]   = ldmix(w_in, tid, m);
    if (tid < HID*OUTDIM) w_out_f[tid]  = ldmix(w_out, tid, m);
    if (tid < INDIM*16)   tau_w1_f[tid] = ldmix(tau_w1, tid, m);
    if (tid < HID)    smallf[tid]       = ldmix(b_in, tid, m);
    if (tid < THID) { smallf[96+tid]    = ldmix(bih, tid, m);
                      smallf[384+tid]   = ldmix(bhh, tid, m); }
    if (tid < OUTDIM) smallf[672+tid]   = ldmix(b_out, tid, m);
    if (tid < 16)   { smallf[736+tid]   = ldmix(tau_w2, tid, m);
                      smallf[752+tid]   = ldmix(tau_b1, tid, m); }
    if (tid == 0)     smallf[768]       = ldmix(tau_b2, 0, m);
}

// ---------------- h0 = relu(x @ w_in + b_in) ----------------
__global__ void h0_kernel(const float* __restrict__ x_f, const float* __restrict__ w_in_f,
                          const float* __restrict__ smallf, float* __restrict__ h, int N) {
    int tid = blockIdx.x*blockDim.x + threadIdx.x;
    if (tid >= N*HID) return;
    int n = tid / HID, j = tid % HID;
    const float* xr = x_f + (size_t)n*INDIM;
    float acc = smallf[j];
    #pragma unroll 8
    for (int k = 0; k < INDIM; k++) acc += xr[k] * w_in_f[k*HID + j];
    h[tid] = fmaxf(acc, 0.f);
}

// ---------------- tau MLP -> steps, and histogram of steps ----------------
__global__ void tau_kernel(const float* __restrict__ x_f, const float* __restrict__ tau_w1_f,
                           const float* __restrict__ smallf,
                           int* __restrict__ steps, int* cnt6, int N) {
    int n = blockIdx.x*blockDim.x + threadIdx.x;
    if (n >= N) return;
    const float* xr = x_f + (size_t)n*INDIM;
    float acc[16];
    #pragma unroll
    for (int j = 0; j < 16; j++) acc[j] = smallf[752+j];
    for (int k = 0; k < INDIM; k++) {
        float xv = xr[k];
        const float* w = tau_w1_f + k*16;
        #pragma unroll
        for (int j = 0; j < 16; j++) acc[j] += xv * w[j];
    }
    float z = smallf[768];
    #pragma unroll
    for (int j = 0; j < 16; j++) z += fmaxf(acc[j], 0.f) * smallf[736+j];
    // softplus, stable form: max(z,0) + log1p(exp(-|z|))
    float tau = fmaxf(z, 0.f) + log1pf(expf(-fabsf(z)));
    float inv = 1.0f / tau;
    int s;
    if (inv >= 5.0f) s = 5;
    else { s = (int)inv; if (s < 0) s = 0; if (s > 5) s = 5; }
    steps[n] = s;
    atomicAdd(&cnt6[s], 1);
}

// ---------------- CSR build ----------------
__global__ void deg_kernel(const int* __restrict__ row, int* deg, int E) {
    int e = blockIdx.x*blockDim.x + threadIdx.x;
    if (e < E) atomicAdd(&deg[row[e]], 1);
}

// single-block scan: off = exclusive_scan(deg); also bucket starts (descending steps)
__global__ void scan_kernel(const int* __restrict__ deg, int* __restrict__ off,
                            const int* __restrict__ cnt6, int* __restrict__ bstart, int N) {
    __shared__ int buf[1024];
    int tid = threadIdx.x;
    int C = (N + 1023) / 1024;
    int start = tid * C, end = min(start + C, N);
    if (end < start) end = start;
    int s = 0;
    for (int i = start; i < end; i++) s += deg[i];
    buf[tid] = s; __syncthreads();
    for (int ofs = 1; ofs < 1024; ofs <<= 1) {
        int t = (tid >= ofs) ? buf[tid - ofs] : 0;
        __syncthreads();
        buf[tid] += t;
        __syncthreads();
    }
    int incl = buf[tid];
    int run = incl - s;                 // exclusive prefix for this chunk
    for (int i = start; i < end; i++) { off[i] = run; run += deg[i]; }
    if (tid == 1023) off[N] = incl;     // = E
    if (tid == 0) {
        int running = 0;
        for (int ss = 5; ss >= 0; --ss) { bstart[ss] = running; running += cnt6[ss]; }
        bstart[6] = running;            // = N
    }
}

__global__ void fill_kernel(const int* __restrict__ row, const int* __restrict__ col,
                            const int* __restrict__ off, int* cur, int* __restrict__ csr_col, int E) {
    int e = blockIdx.x*blockDim.x + threadIdx.x;
    if (e >= E) return;
    int r = row[e];
    int p = atomicAdd(&cur[r], 1);
    csr_col[off[r] + p] = col[e];
}

// order nodes by descending steps (counting-sort scatter). K[t] = bstart[t].
__global__ void order_kernel(const int* __restrict__ steps, const int* __restrict__ bstart,
                             int* cur6, int* __restrict__ order, int N) {
    int n = blockIdx.x*blockDim.x + threadIdx.x;
    if (n >= N) return;
    int s = steps[n];
    int p = atomicAdd(&cur6[s], 1);
    order[bstart[s] + p] = n;
}

// ---------------- iteration kernels (grid-stride; active count read from device) ----------------
__global__ void agg_kernel(const float* __restrict__ h, const int* __restrict__ off,
                           const int* __restrict__ csr_col, const int* __restrict__ order,
                           const int* __restrict__ bstart, int t, float* __restrict__ agg) {
    int K = bstart[t];
    int total = K * HID;
    int stride = gridDim.x * blockDim.x;
    for (int idx = blockIdx.x*blockDim.x + threadIdx.x; idx < total; idx += stride) {
        int li = idx / HID, f = idx % HID;
        int i = order[li];
        float hv = h[i*HID + f];
        int e0 = off[i], e1 = off[i+1];
        float acc = 0.f;
        for (int e = e0; e < e1; e++) {
            int c = csr_col[e];
            acc += fabsf(hv - h[c*HID + f]);
        }
        agg[i*HID + f] = acc;
    }
}

__global__ void gru_kernel(const float* __restrict__ h, const float* __restrict__ agg,
                           const float* __restrict__ wihT, const float* __restrict__ whhT,
                           const float* __restrict__ smallf, const int* __restrict__ order,
                           const int* __restrict__ bstart, int t, float* __restrict__ hnew) {
    int K = bstart[t];
    int tiles = (K + NT - 1) / NT;
    int total = tiles * HID;
    int stride = gridDim.x * blockDim.x;
    for (int idx = blockIdx.x*blockDim.x + threadIdx.x; idx < total; idx += stride) {
        int tile = idx / HID, jj = idx % HID;
        int n[NT]; bool valid[NT];
        #pragma unroll
        for (int u = 0; u < NT; u++) {
            int li = tile*NT + u;
            valid[u] = li < K;
            n[u] = valid[u] ? order[li] : order[0];
        }
        float gri[NT], gzi[NT], gni[NT], grh[NT], gzh[NT], gnh[NT];
        #pragma unroll
        for (int u = 0; u < NT; u++) { gri[u]=gzi[u]=gni[u]=grh[u]=gzh[u]=gnh[u]=0.f; }
        for (int k = 0; k < HID; k++) {
            const float* wi = wihT + k*THID;
            const float* wh = whhT + k*THID;
            float wi0 = wi[jj], wi1 = wi[HID+jj], wi2 = wi[2*HID+jj];
            float wh0 = wh[jj], wh1 = wh[HID+jj], wh2 = wh[2*HID+jj];
            #pragma unroll
            for (int u = 0; u < NT; u++) {
                float a  = agg[n[u]*HID + k];
                float hv = h  [n[u]*HID + k];
                gri[u] += a*wi0;  gzi[u] += a*wi1;  gni[u] += a*wi2;
                grh[u] += hv*wh0; gzh[u] += hv*wh1; gnh[u] += hv*wh2;
            }
        }
        float bir = smallf[96+jj],  biz = smallf[96+HID+jj],  bin = smallf[96+2*HID+jj];
        float bhr = smallf[384+jj], bhz = smallf[384+HID+jj], bhn = smallf[384+2*HID+jj];
        #pragma unroll
        for (int u = 0; u < NT; u++) {
            if (!valid[u]) continue;
            float r  = 1.f/(1.f + expf(-(gri[u]+bir + grh[u]+bhr)));
            float z  = 1.f/(1.f + expf(-(gzi[u]+biz + gzh[u]+bhz)));
            float nn = tanhf(gni[u]+bin + r*(gnh[u]+bhn));
            float hv = h[n[u]*HID + jj];
            hnew[n[u]*HID + jj] = (1.f - z)*nn + z*hv;
        }
    }
}

__global__ void commit_kernel(float* __restrict__ h, const float* __restrict__ hnew,
                              const int* __restrict__ order, const int* __restrict__ bstart, int t) {
    int K = bstart[t];
    int total = K * HID;
    int stride = gridDim.x * blockDim.x;
    for (int idx = blockIdx.x*blockDim.x + threadIdx.x; idx < total; idx += stride) {
        int li = idx / HID, f = idx % HID;
        int i = order[li];
        h[i*HID + f] = hnew[i*HID + f];
    }
}

// ---------------- out = h @ w_out + b_out (dtype per mode) ----------------
__global__ void out_kernel(const float* __restrict__ h, const float* __restrict__ w_out_f,
                           const float* __restrict__ smallf, void* out, const int* mode, int N) {
    int tid = blockIdx.x*blockDim.x + threadIdx.x;
    if (tid >= N*OUTDIM) return;
    int n = tid / OUTDIM, o = tid % OUTDIM;
    float acc = smallf[672+o];
    const float* hr = h + n*HID;
    #pragma unroll 8
    for (int k = 0; k < HID; k++) acc += hr[k] * w_out_f[k*OUTDIM + o];
    if (*mode) ((float*)out)[tid] = acc;
    else       ((__hip_bfloat16*)out)[tid] = __float2bfloat16(acc);
}

extern "C" void kernel_launch(void* const* d_in, const int* in_sizes, int n_in,
                              void* d_out, int out_size, void* d_ws, size_t ws_size,
                              hipStream_t stream) {
    const void* x      = d_in[0];
    const int*  ei     = (const int*)d_in[1];
    const void* w_in   = d_in[2],  *b_in   = d_in[3];
    const void* tau_w1 = d_in[4],  *tau_b1 = d_in[5];
    const void* tau_w2 = d_in[6],  *tau_b2 = d_in[7];
    const void* wih    = d_in[8],  *whh    = d_in[9];
    const void* bih    = d_in[10], *bhh    = d_in[11];
    const void* w_out  = d_in[12], *b_out  = d_in[13];

    int N = in_sizes[0] / INDIM;
    int E = in_sizes[1] / 2;
    const int* row = ei;
    const int* col = ei + E;

    char* ws = (char*)d_ws;
    size_t o = 0;
    auto take = [&](size_t bytes) -> char* {
        char* p = ws + o;
        o = (o + bytes + 255) & ~(size_t)255;
        return p;
    };
    float* x_f      = (float*)take((size_t)N*INDIM*4);
    float* h        = (float*)take((size_t)N*HID*4);
    float* agg      = (float*)take((size_t)N*HID*4);
    float* hnew     = (float*)take((size_t)N*HID*4);
    float* wihT     = (float*)take((size_t)THID*HID*4);
    float* whhT     = (float*)take((size_t)THID*HID*4);
    float* w_in_f   = (float*)take((size_t)INDIM*HID*4);
    float* w_out_f  = (float*)take((size_t)HID*OUTDIM*4);
    float* tau_w1_f = (float*)take((size_t)INDIM*16*4);
    float* smallf   = (float*)take(1024*4);
    int*   off      = (int*)take((size_t)(N+1)*4);
    int*   csr_col  = (int*)take((size_t)E*4);
    int*   order    = (int*)take((size_t)N*4);
    int*   steps    = (int*)take((size_t)N*4);
    int*   bstart   = (int*)take(64);
    int*   mode     = (int*)take(64);
    // zero region (memset each launch): deg, cur, cnt6, cur6
    char*  zbase    = ws + o;
    int*   deg      = (int*)take((size_t)N*4);
    int*   cur      = (int*)take((size_t)N*4);
    int*   cnt6     = (int*)take(64);
    int*   cur6     = (int*)take(64);
    size_t zbytes   = (size_t)((ws + o) - zbase);

    hipMemsetAsync(zbase, 0, zbytes, stream);
    sniff_kernel<<<1, 64, 0, stream>>>((const unsigned int*)x, mode);

    xconv_kernel<<<(N*INDIM + 255)/256, 256, 0, stream>>>(x, x_f, mode, N*INDIM);
    prep_kernel<<<(THID*HID + 255)/256, 256, 0, stream>>>(
        w_in, b_in, tau_w1, tau_b1, tau_w2, tau_b2, wih, whh, bih, bhh, w_out, b_out,
        wihT, whhT, w_in_f, w_out_f, tau_w1_f, smallf, mode);

    h0_kernel<<<(N*HID + 255)/256, 256, 0, stream>>>(x_f, w_in_f, smallf, h, N);
    tau_kernel<<<(N + 255)/256, 256, 0, stream>>>(x_f, tau_w1_f, smallf, steps, cnt6, N);
    deg_kernel<<<(E + 255)/256, 256, 0, stream>>>(row, deg, E);
    scan_kernel<<<1, 1024, 0, stream>>>(deg, off, cnt6, bstart, N);
    fill_kernel<<<(E + 255)/256, 256, 0, stream>>>(row, col, off, cur, csr_col, E);
    order_kernel<<<(N + 255)/256, 256, 0, stream>>>(steps, bstart, cur6, order, N);

    for (int t = 0; t < 5; t++) {
        agg_kernel<<<4096, 256, 0, stream>>>(h, off, csr_col, order, bstart, t, agg);
        gru_kernel<<<2048, 256, 0, stream>>>(h, agg, wihT, whhT, smallf, order, bstart, t, hnew);
        commit_kernel<<<2048, 256, 0, stream>>>(h, hnew, order, bstart, t);
    }

    out_kernel<<<(N*OUTDIM + 255)/256, 256, 0, stream>>>(h, w_out_f, smallf, d_out, mode, N);
}